// Round 1
// baseline (3563.225 us; speedup 1.0000x reference)
//
#include <hip/hip_runtime.h>
#include <hip/hip_bf16.h>

#define BB 64
#define SS 333
#define NH 8
#define DH 64
#define NI 512
#define DM 333
#define KS 66   // LDS row stride (bf16 elems) for K/V/Er tiles: 132B rows -> conflict-free

__device__ inline float bf_lo(unsigned int w) { return __uint_as_float(w << 16); }
__device__ inline float bf_hi(unsigned int w) { return __uint_as_float(w & 0xffff0000u); }

// ---------------- K1: x = emb[xs]; Q/K/V = x@W + b; store as (B,H,S,DH) ----------------
__global__ __launch_bounds__(256) void qkv_kernel(
    const int* __restrict__ xs, const float* __restrict__ emb,
    const float* __restrict__ Wq, const float* __restrict__ bq,
    const float* __restrict__ Wk, const float* __restrict__ bk,
    const float* __restrict__ Wv, const float* __restrict__ bv,
    float* __restrict__ qkv)
{
    __shared__ float xt[16][DM];
    __shared__ int toks[16];
    const int row0 = blockIdx.x * 16;
    const int chunk = blockIdx.y;           // 0..5: (mat, col-half)
    const int t = threadIdx.x;

    if (t < 16) toks[t] = xs[row0 + t];
    __syncthreads();
    for (int idx = t; idx < 16 * DM; idx += 256) {
        int r = idx / DM, c2 = idx - r * DM;
        xt[r][c2] = emb[(size_t)toks[r] * DM + c2];
    }
    __syncthreads();

    const int mat = chunk >> 1;
    const float* W    = (mat == 0) ? Wq : (mat == 1) ? Wk : Wv;
    const float* bias = (mat == 0) ? bq : (mat == 1) ? bk : bv;
    const int c = ((chunk & 1) << 8) + t;   // 0..511

    float acc[16];
#pragma unroll
    for (int r = 0; r < 16; ++r) acc[r] = 0.f;
    for (int k = 0; k < DM; ++k) {
        float w = W[(size_t)k * NI + c];
#pragma unroll
        for (int r = 0; r < 16; ++r) acc[r] = fmaf(xt[r][k], w, acc[r]);
    }

    const float bb = bias[c];
    const int h = c >> 6, d = c & 63;
    const size_t N = (size_t)BB * NH * SS * DH;
    float* dst = qkv + (size_t)mat * N;
#pragma unroll
    for (int r = 0; r < 16; ++r) {
        int grow = row0 + r;
        int b = grow / SS, s = grow - b * SS;
        dst[(((size_t)b * NH + h) * SS + s) * DH + d] = acc[r] + bb;
    }
}

// ---------------- K2: per-(b,h) causal attention with skewed relative scores ----------------
// srel[i,j] = q_i . Er[SS-1-i+j]  (j<=i)
__global__ __launch_bounds__(256) void attn_kernel(
    const float* __restrict__ qkv, const float* __restrict__ Er,
    float* __restrict__ attn)
{
    __shared__ __hip_bfloat16 kt[SS * KS];
    __shared__ __hip_bfloat16 vt[SS * KS];
    __shared__ __hip_bfloat16 et[SS * KS];
    __shared__ float qrow[DH];
    __shared__ float pbuf[SS];
    __shared__ float red[8];
    __shared__ float outred[4][DH];

    const int bh = blockIdx.x;              // 0..511
    const int b = bh >> 3, h = bh & 7;
    const size_t N = (size_t)BB * NH * SS * DH;
    const float* qp = qkv + ((size_t)b * NH + h) * SS * DH;
    const float* kp = qp + N;
    const float* vp = qp + 2 * N;
    const int t = threadIdx.x;
    const int lane = t & 63, wid = t >> 6;

    for (int idx = t; idx < SS * DH; idx += 256) {
        int j = idx >> 6, d = idx & 63;
        kt[j * KS + d] = __float2bfloat16(kp[idx]);
        vt[j * KS + d] = __float2bfloat16(vp[idx]);
        et[j * KS + d] = __float2bfloat16(Er[idx]);
    }
    __syncthreads();

    for (int i = 0; i < SS; ++i) {
        if (t < DH) qrow[t] = qp[(size_t)i * DH + t];
        __syncthreads();                                   // (A)

        float sc[2]; float lmax = -1e30f;
#pragma unroll
        for (int rr = 0; rr < 2; ++rr) {
            const int j = t + rr * 256;
            sc[rr] = -1e30f;
            if (j <= i) {
                const unsigned int* krow = (const unsigned int*)(kt + j * KS);
                const unsigned int* erow = (const unsigned int*)(et + (SS - 1 - i + j) * KS);
                float a1 = 0.f, a2 = 0.f;
#pragma unroll 8
                for (int dd = 0; dd < DH / 2; ++dd) {
                    unsigned int kw = krow[dd], ew = erow[dd];
                    float q0 = qrow[2 * dd], q1 = qrow[2 * dd + 1];
                    a1 = fmaf(q0, bf_lo(kw), a1);
                    a1 = fmaf(q1, bf_hi(kw), a1);
                    a2 = fmaf(q0, bf_lo(ew), a2);
                    a2 = fmaf(q1, bf_hi(ew), a2);
                }
                sc[rr] = (a1 + a2) * 0.125f;
                lmax = fmaxf(lmax, sc[rr]);
            }
        }
        // block max
#pragma unroll
        for (int off = 32; off >= 1; off >>= 1) lmax = fmaxf(lmax, __shfl_xor(lmax, off));
        if (lane == 0) red[wid] = lmax;
        __syncthreads();                                   // (B)
        const float m = fmaxf(fmaxf(red[0], red[1]), fmaxf(red[2], red[3]));

        float lsum = 0.f;
#pragma unroll
        for (int rr = 0; rr < 2; ++rr) {
            const int j = t + rr * 256;
            if (j <= i) {
                float p = __expf(sc[rr] - m);
                pbuf[j] = p;
                lsum += p;
            }
        }
#pragma unroll
        for (int off = 32; off >= 1; off >>= 1) lsum += __shfl_xor(lsum, off);
        if (lane == 0) red[4 + wid] = lsum;
        __syncthreads();                                   // (C)
        const float inv = 1.f / (red[4] + red[5] + red[6] + red[7]);

        // out_d = sum_j p_j * v[j,d]; wave 'wid' takes j = wid, wid+4, ...
        float acc = 0.f;
        for (int j = wid; j <= i; j += 4)
            acc = fmaf(pbuf[j], __bfloat162float(vt[j * KS + lane]), acc);
        outred[wid][lane] = acc;
        __syncthreads();                                   // (D)
        if (wid == 0) {
            float o = (outred[0][lane] + outred[1][lane] + outred[2][lane] + outred[3][lane]) * inv;
            attn[(((size_t)b * SS + i) * NH + h) * DH + lane] = o;  // (B,S,INNER) layout
        }
        __syncthreads();                                   // (E)
    }
}

// ---------------- K3: out = attn @ Wo + bo ----------------
__global__ __launch_bounds__(256) void oproj_kernel(
    const float* __restrict__ attn, const float* __restrict__ Wo,
    const float* __restrict__ bo, float* __restrict__ out)
{
    __shared__ float at[8][NI];
    const int row0 = blockIdx.x * 8;
    const int t = threadIdx.x;
    for (int idx = t; idx < 8 * NI; idx += 256) {
        int r = idx >> 9, k = idx & (NI - 1);
        at[r][k] = attn[(size_t)(row0 + r) * NI + k];
    }
    __syncthreads();

    const int c0 = t;
    const int c1 = t + 256;
    const bool has1 = (c1 < DM);
    float acc0[8], acc1[8];
#pragma unroll
    for (int r = 0; r < 8; ++r) { acc0[r] = 0.f; acc1[r] = 0.f; }
    for (int k = 0; k < NI; ++k) {
        float w0 = Wo[(size_t)k * DM + c0];
        float w1 = has1 ? Wo[(size_t)k * DM + c1] : 0.f;
#pragma unroll
        for (int r = 0; r < 8; ++r) {
            float a = at[r][k];
            acc0[r] = fmaf(a, w0, acc0[r]);
            acc1[r] = fmaf(a, w1, acc1[r]);
        }
    }
    const float b0 = bo[c0];
    const float b1 = has1 ? bo[c1] : 0.f;
#pragma unroll
    for (int r = 0; r < 8; ++r) {
        out[(size_t)(row0 + r) * DM + c0] = acc0[r] + b0;
        if (has1) out[(size_t)(row0 + r) * DM + c1] = acc1[r] + b1;
    }
}

extern "C" void kernel_launch(void* const* d_in, const int* in_sizes, int n_in,
                              void* d_out, int out_size, void* d_ws, size_t ws_size,
                              hipStream_t stream) {
    const int*   xs  = (const int*)d_in[0];
    const float* emb = (const float*)d_in[1];
    const float* Wq  = (const float*)d_in[2];
    const float* bq  = (const float*)d_in[3];
    const float* Wk  = (const float*)d_in[4];
    const float* bk  = (const float*)d_in[5];
    const float* Wv  = (const float*)d_in[6];
    const float* bv  = (const float*)d_in[7];
    const float* Er  = (const float*)d_in[8];
    const float* Wo  = (const float*)d_in[9];
    const float* bo  = (const float*)d_in[10];
    float* out = (float*)d_out;

    const size_t N = (size_t)BB * NH * SS * DH;   // 10,911,744
    float* qkv  = (float*)d_ws;                   // 3N floats (Q,K,V)
    float* attn = qkv + 3 * N;                    // N floats

    dim3 g1((BB * SS) / 16, 6);
    qkv_kernel<<<g1, 256, 0, stream>>>(xs, emb, Wq, bq, Wk, bk, Wv, bv, qkv);
    attn_kernel<<<BB * NH, 256, 0, stream>>>(qkv, Er, attn);
    oproj_kernel<<<(BB * SS) / 8, 256, 0, stream>>>(attn, Wo, bo, out);
}

// Round 2
// 937.972 us; speedup vs baseline: 3.7989x; 3.7989x over previous
//
#include <hip/hip_runtime.h>
#include <hip/hip_bf16.h>

#define BB 64
#define SS 333
#define NH 8
#define DH 64
#define NI 512
#define DM 333

typedef __attribute__((ext_vector_type(8))) short short8v;
typedef __attribute__((ext_vector_type(4))) short short4v;
typedef __attribute__((ext_vector_type(4))) float f32x4;

__device__ inline short f2bf(float f) {
    unsigned u = __float_as_uint(f);
    u += 0x7fffu + ((u >> 16) & 1u);
    return (short)(u >> 16);
}

// ---------------- K0: Er f32 -> bf16 ----------------
__global__ __launch_bounds__(256) void er_conv_kernel(const float* __restrict__ Er,
                                                      short* __restrict__ eb) {
    int i = blockIdx.x * 256 + threadIdx.x;
    if (i < SS * DH) eb[i] = f2bf(Er[i]);
}

// ---------------- K1: x = emb[xs]; Q/K/V = x@W + b; store bf16 (B,H,S,DH) ----------------
__global__ __launch_bounds__(256) void qkv_kernel(
    const int* __restrict__ xs, const float* __restrict__ emb,
    const float* __restrict__ Wq, const float* __restrict__ bq,
    const float* __restrict__ Wk, const float* __restrict__ bk,
    const float* __restrict__ Wv, const float* __restrict__ bv,
    short* __restrict__ qb, short* __restrict__ kbf, short* __restrict__ vbf)
{
    __shared__ float xt[16][DM];
    __shared__ int toks[16];
    const int row0 = blockIdx.x * 16;
    const int chunk = blockIdx.y;           // 0..5: (mat, col-half)
    const int t = threadIdx.x;

    if (t < 16) toks[t] = xs[row0 + t];
    __syncthreads();
    for (int idx = t; idx < 16 * DM; idx += 256) {
        int r = idx / DM, c2 = idx - r * DM;
        xt[r][c2] = emb[(size_t)toks[r] * DM + c2];
    }
    __syncthreads();

    const int mat = chunk >> 1;
    const float* W    = (mat == 0) ? Wq : (mat == 1) ? Wk : Wv;
    const float* bias = (mat == 0) ? bq : (mat == 1) ? bk : bv;
    const int c = ((chunk & 1) << 8) + t;   // 0..511

    float acc[16];
#pragma unroll
    for (int r = 0; r < 16; ++r) acc[r] = 0.f;
    for (int k = 0; k < DM; ++k) {
        float w = W[(size_t)k * NI + c];
#pragma unroll
        for (int r = 0; r < 16; ++r) acc[r] = fmaf(xt[r][k], w, acc[r]);
    }

    const float bb = bias[c];
    const int h = c >> 6, d = c & 63;
    short* dst = (mat == 0) ? qb : (mat == 1) ? kbf : vbf;
#pragma unroll
    for (int r = 0; r < 16; ++r) {
        int grow = row0 + r;
        int b = grow / SS, s = grow - b * SS;
        dst[(((size_t)b * NH + h) * SS + s) * DH + d] = f2bf(acc[r] + bb);
    }
}

// ---------------- K2: flash-style MFMA attention with skewed relative scores ----------------
// scores[i][j] = (q_i.k_j + q_i.Er[SS-1-i+j]) / 8, causal
__global__ __launch_bounds__(256) void attn_mfma_kernel(
    const short* __restrict__ qb, const short* __restrict__ kb,
    const short* __restrict__ vb, const short* __restrict__ eb,
    float* __restrict__ attnout)
{
    __shared__ short k_lds[64 * 64];        // [key][d], 128B rows, XOR-swizzled
    __shared__ short v_lds[64 * 64];        // [d][key] (transposed), swizzled
    __shared__ short er_lds[144 * 64];      // Er band rows, swizzled
    __shared__ float qe_lds[4][16 * 80];    // per-wave QE band (f32)
    __shared__ short p_lds[4][16 * 64];     // per-wave P tile (bf16), swizzled

    const int bid = blockIdx.x;
    const int bh = bid / 6, qt = bid - bh * 6;
    const int b = bh >> 3, h = bh & 7;
    const int i0 = qt * 64;
    const int t = threadIdx.x;
    const int lane = t & 63, w = t >> 6;
    const int l15 = lane & 15, lq = lane >> 4;
    const size_t base = (size_t)bh * SS * DH;

    // Q fragments (A): row m = l15, k = lq*8+e
    const int iw = i0 + 16 * w;
    int qr = iw + l15; if (qr > SS - 1) qr = SS - 1;
    const short8v qa0 = *(const short8v*)(qb + base + (size_t)qr * DH + lq * 8);
    const short8v qa1 = *(const short8v*)(qb + base + (size_t)qr * DH + 32 + lq * 8);

    float m[4], l[4];
    f32x4 o[4];
#pragma unroll
    for (int r = 0; r < 4; ++r) { m[r] = -1e30f; l[r] = 0.f; }
#pragma unroll
    for (int nd = 0; nd < 4; ++nd) { f32x4 z = {0.f, 0.f, 0.f, 0.f}; o[nd] = z; }

    const int nst = qt + 1;
    for (int js = 0; js < nst; ++js) {
        const int j0 = js * 64;
        __syncthreads();
        // ---- stage K tile: 64 keys x 64 d ----
#pragma unroll
        for (int it = 0; it < 2; ++it) {
            int task = t + 256 * it;
            int row = task >> 3, c = task & 7;
            int jg = j0 + row; if (jg > SS - 1) jg = SS - 1;
            short8v kv = *(const short8v*)(kb + base + (size_t)jg * DH + c * 8);
            *(short8v*)((char*)k_lds + ((row * 128 + c * 16) ^ ((row & 7) << 4))) = kv;
        }
        // ---- stage V transposed: v_lds[d][key] ----
        if (t < 128) {
            int qd = t >> 3, c = t & 7;
            int j00 = j0 + qd * 4;
            int ja = j00     > SS - 1 ? SS - 1 : j00;
            int jb2 = j00 + 1 > SS - 1 ? SS - 1 : j00 + 1;
            int jc = j00 + 2 > SS - 1 ? SS - 1 : j00 + 2;
            int jd2 = j00 + 3 > SS - 1 ? SS - 1 : j00 + 3;
            short8v r0 = *(const short8v*)(vb + base + (size_t)ja * DH + c * 8);
            short8v r1 = *(const short8v*)(vb + base + (size_t)jb2 * DH + c * 8);
            short8v r2 = *(const short8v*)(vb + base + (size_t)jc * DH + c * 8);
            short8v r3 = *(const short8v*)(vb + base + (size_t)jd2 * DH + c * 8);
#pragma unroll
            for (int dd = 0; dd < 8; ++dd) {
                int d = c * 8 + dd;
                short4v pk; pk[0] = r0[dd]; pk[1] = r1[dd]; pk[2] = r2[dd]; pk[3] = r3[dd];
                *(short4v*)((char*)v_lds + ((d * 128 + qd * 8) ^ ((d & 7) << 4))) = pk;
            }
        }
        // ---- stage Er band: 144 rows from l0blk ----
        const int l0blk = SS - 64 - i0 + j0;
#pragma unroll
        for (int it = 0; it < 5; ++it) {
            int task = t + 256 * it;
            if (task < 144 * 8) {
                int row = task >> 3, c = task & 7;
                int lg = l0blk + row;
                lg = lg < 0 ? 0 : (lg > SS - 1 ? SS - 1 : lg);
                short8v ev = *(const short8v*)(eb + (size_t)lg * DH + c * 8);
                *(short8v*)((char*)er_lds + ((row * 128 + c * 16) ^ ((row & 7) << 4))) = ev;
            }
        }
        __syncthreads();

        // ---- QE band: 5 n-tiles of 16 l's ----
        const int sbase = 48 - 16 * w;
        f32x4 qe[5];
#pragma unroll
        for (int n2 = 0; n2 < 5; ++n2) {
            int slot = sbase + n2 * 16 + l15;
            short8v e0 = *(const short8v*)((char*)er_lds + ((slot * 128 + lq * 16) ^ ((slot & 7) << 4)));
            short8v e1 = *(const short8v*)((char*)er_lds + ((slot * 128 + 64 + lq * 16) ^ ((slot & 7) << 4)));
            f32x4 z = {0.f, 0.f, 0.f, 0.f};
            z = __builtin_amdgcn_mfma_f32_16x16x32_bf16(qa0, e0, z, 0, 0, 0);
            qe[n2] = __builtin_amdgcn_mfma_f32_16x16x32_bf16(qa1, e1, z, 0, 0, 0);
        }
        float* qeb = qe_lds[w];
#pragma unroll
        for (int n2 = 0; n2 < 5; ++n2)
#pragma unroll
            for (int r = 0; r < 4; ++r)
                qeb[(lq * 4 + r) * 80 + n2 * 16 + l15] = qe[n2][r];

        // ---- QK: 4 n-tiles of 16 keys ----
        f32x4 sc[4];
#pragma unroll
        for (int n = 0; n < 4; ++n) {
            int row = n * 16 + l15;
            short8v k0 = *(const short8v*)((char*)k_lds + ((row * 128 + lq * 16) ^ ((row & 7) << 4)));
            short8v k1 = *(const short8v*)((char*)k_lds + ((row * 128 + 64 + lq * 16) ^ ((row & 7) << 4)));
            f32x4 z = {0.f, 0.f, 0.f, 0.f};
            z = __builtin_amdgcn_mfma_f32_16x16x32_bf16(qa0, k0, z, 0, 0, 0);
            sc[n] = __builtin_amdgcn_mfma_f32_16x16x32_bf16(qa1, k1, z, 0, 0, 0);
        }

        // ---- combine + skew-gather + causal mask ----
#pragma unroll
        for (int n = 0; n < 4; ++n)
#pragma unroll
            for (int r = 0; r < 4; ++r) {
                int irel = lq * 4 + r;
                int jrel = n * 16 + l15;
                float srel = qeb[irel * 80 + (15 - irel + jrel)];
                float s = (sc[n][r] + srel) * 0.125f;
                bool ok = (j0 + jrel) <= (iw + irel);
                sc[n][r] = ok ? s : -1e9f;
            }

        // ---- online softmax (per row r, 16-lane groups) ----
        float scale[4];
#pragma unroll
        for (int r = 0; r < 4; ++r) {
            float mx = fmaxf(fmaxf(sc[0][r], sc[1][r]), fmaxf(sc[2][r], sc[3][r]));
            mx = fmaxf(mx, __shfl_xor(mx, 1));
            mx = fmaxf(mx, __shfl_xor(mx, 2));
            mx = fmaxf(mx, __shfl_xor(mx, 4));
            mx = fmaxf(mx, __shfl_xor(mx, 8));
            float mn = fmaxf(m[r], mx);
            scale[r] = __expf(m[r] - mn);
            m[r] = mn;
            float ps = 0.f;
#pragma unroll
            for (int n = 0; n < 4; ++n) {
                float p = __expf(sc[n][r] - mn);
                sc[n][r] = p;
                ps += p;
            }
            ps += __shfl_xor(ps, 1);
            ps += __shfl_xor(ps, 2);
            ps += __shfl_xor(ps, 4);
            ps += __shfl_xor(ps, 8);
            l[r] = l[r] * scale[r] + ps;
        }

        // ---- P -> bf16 -> LDS ----
        short* pw = p_lds[w];
#pragma unroll
        for (int n = 0; n < 4; ++n)
#pragma unroll
            for (int r = 0; r < 4; ++r) {
                int irel = lq * 4 + r;
                int jrel = n * 16 + l15;
                *(short*)((char*)pw + ((irel * 128 + jrel * 2) ^ ((irel & 7) << 4))) = f2bf(sc[n][r]);
            }

        // ---- rescale O ----
#pragma unroll
        for (int nd = 0; nd < 4; ++nd)
#pragma unroll
            for (int r = 0; r < 4; ++r)
                o[nd][r] *= scale[r];

        // ---- PV ----
#pragma unroll
        for (int kb2 = 0; kb2 < 2; ++kb2) {
            short8v pa = *(const short8v*)((char*)pw + ((l15 * 128 + kb2 * 64 + lq * 16) ^ ((l15 & 7) << 4)));
#pragma unroll
            for (int nd = 0; nd < 4; ++nd) {
                int d = nd * 16 + l15;
                short8v vf = *(const short8v*)((char*)v_lds + ((d * 128 + kb2 * 64 + lq * 16) ^ ((d & 7) << 4)));
                o[nd] = __builtin_amdgcn_mfma_f32_16x16x32_bf16(pa, vf, o[nd], 0, 0, 0);
            }
        }
    }

    // ---- epilogue: normalize + store (B,S,H,DH) f32 ----
#pragma unroll
    for (int r = 0; r < 4; ++r) {
        int i = iw + lq * 4 + r;
        if (i < SS) {
            float rl = 1.0f / l[r];
#pragma unroll
            for (int nd = 0; nd < 4; ++nd)
                attnout[(((size_t)b * SS + i) * NH + h) * DH + nd * 16 + l15] = o[nd][r] * rl;
        }
    }
}

// ---------------- K3: out = attn @ Wo + bo ----------------
__global__ __launch_bounds__(256) void oproj_kernel(
    const float* __restrict__ attn, const float* __restrict__ Wo,
    const float* __restrict__ bo, float* __restrict__ out)
{
    __shared__ float at[8][NI];
    const int row0 = blockIdx.x * 8;
    const int t = threadIdx.x;
    for (int idx = t; idx < 8 * NI; idx += 256) {
        int r = idx >> 9, k = idx & (NI - 1);
        at[r][k] = attn[(size_t)(row0 + r) * NI + k];
    }
    __syncthreads();

    const int c0 = t;
    const int c1 = t + 256;
    const bool has1 = (c1 < DM);
    float acc0[8], acc1[8];
#pragma unroll
    for (int r = 0; r < 8; ++r) { acc0[r] = 0.f; acc1[r] = 0.f; }
    for (int k = 0; k < NI; ++k) {
        float w0 = Wo[(size_t)k * DM + c0];
        float w1 = has1 ? Wo[(size_t)k * DM + c1] : 0.f;
#pragma unroll
        for (int r = 0; r < 8; ++r) {
            float a = at[r][k];
            acc0[r] = fmaf(a, w0, acc0[r]);
            acc1[r] = fmaf(a, w1, acc1[r]);
        }
    }
    const float b0 = bo[c0];
    const float b1 = has1 ? bo[c1] : 0.f;
#pragma unroll
    for (int r = 0; r < 8; ++r) {
        out[(size_t)(row0 + r) * DM + c0] = acc0[r] + b0;
        if (has1) out[(size_t)(row0 + r) * DM + c1] = acc1[r] + b1;
    }
}

extern "C" void kernel_launch(void* const* d_in, const int* in_sizes, int n_in,
                              void* d_out, int out_size, void* d_ws, size_t ws_size,
                              hipStream_t stream) {
    const int*   xs  = (const int*)d_in[0];
    const float* emb = (const float*)d_in[1];
    const float* Wq  = (const float*)d_in[2];
    const float* bq  = (const float*)d_in[3];
    const float* Wk  = (const float*)d_in[4];
    const float* bk  = (const float*)d_in[5];
    const float* Wv  = (const float*)d_in[6];
    const float* bv  = (const float*)d_in[7];
    const float* Er  = (const float*)d_in[8];
    const float* Wo  = (const float*)d_in[9];
    const float* bo  = (const float*)d_in[10];
    float* out = (float*)d_out;

    const size_t N = (size_t)BB * NH * SS * DH;   // 10,911,744
    short* qb  = (short*)d_ws;
    short* kbf = qb + N;
    short* vbf = kbf + N;
    short* eb  = vbf + N;                         // SS*DH shorts
    float* attn = (float*)(eb + SS * DH);         // N floats (offset is 4B-aligned)

    er_conv_kernel<<<(SS * DH + 255) / 256, 256, 0, stream>>>(Er, eb);
    dim3 g1((BB * SS) / 16, 6);
    qkv_kernel<<<g1, 256, 0, stream>>>(xs, emb, Wq, bq, Wk, bk, Wv, bv, qb, kbf, vbf);
    attn_mfma_kernel<<<BB * NH * 6, 256, 0, stream>>>(qb, kbf, vbf, eb, attn);
    oproj_kernel<<<(BB * SS) / 8, 256, 0, stream>>>(attn, Wo, bo, out);
}

// Round 3
// 215.886 us; speedup vs baseline: 16.5051x; 4.3448x over previous
//
#include <hip/hip_runtime.h>
#include <hip/hip_bf16.h>

#define BB 64
#define SS 333
#define NH 8
#define DH 64
#define NI 512
#define DM 333
#define M1 21312      // BB*SS
#define KP 384        // padded K for qkv GEMM (333 -> 384)
#define NQ 1536       // qkv fused col count
#define RS1 1536      // qkv row stride (shorts)

typedef __attribute__((ext_vector_type(8))) short short8v;
typedef __attribute__((ext_vector_type(4))) short short4v;
typedef __attribute__((ext_vector_type(4))) float f32x4;

__device__ inline short f2bf(float f) {
    unsigned u = __float_as_uint(f);
    u += 0x7fffu + ((u >> 16) & 1u);
    return (short)(u >> 16);
}

__device__ __forceinline__ void gload16(const void* g, void* l) {
    __builtin_amdgcn_global_load_lds(
        (const __attribute__((address_space(1))) void*)g,
        (__attribute__((address_space(3))) void*)l, 16, 0, 0);
}

// ---------------- conversions ----------------
__global__ __launch_bounds__(256) void er_conv_kernel(const float* __restrict__ Er,
                                                      short* __restrict__ eb) {
    int i = blockIdx.x * 256 + threadIdx.x;
    if (i < SS * DH) eb[i] = f2bf(Er[i]);
}

__global__ __launch_bounds__(256) void emb_conv_kernel(const float* __restrict__ emb,
                                                       short* __restrict__ embb) {
    int i = blockIdx.x * 256 + threadIdx.x;
    if (i >= DM * KP) return;
    int v = i / KP, k = i - v * KP;
    embb[i] = (k < DM) ? f2bf(emb[(size_t)v * DM + k]) : (short)0;
}

__global__ __launch_bounds__(256) void w_conv_kernel(const float* __restrict__ Wq,
                                                     const float* __restrict__ Wk,
                                                     const float* __restrict__ Wv,
                                                     short* __restrict__ wt) {
    int i = blockIdx.x * 256 + threadIdx.x;
    if (i >= NQ * KP) return;
    int n = i / KP, k = i - n * KP;
    int mat = n >> 9, c = n & 511;
    const float* W = (mat == 0) ? Wq : (mat == 1) ? Wk : Wv;
    wt[i] = (k < DM) ? f2bf(W[(size_t)k * NI + c]) : (short)0;
}

__global__ __launch_bounds__(256) void wo_conv_kernel(const float* __restrict__ Wo,
                                                      short* __restrict__ wot) {
    int i = blockIdx.x * 256 + threadIdx.x;
    if (i >= 384 * NI) return;
    int n = i >> 9, k = i & 511;
    wot[i] = (n < DM) ? f2bf(Wo[(size_t)k * DM + n]) : (short)0;
}

// ---------------- K1: QKV = gather(emb)[M1,KP] @ wt^T[KP,NQ], bf16 MFMA ----------------
__global__ __launch_bounds__(256) void qkv_mfma_kernel(
    const int* __restrict__ xs, const short* __restrict__ embb,
    const short* __restrict__ wt,
    const float* __restrict__ bq, const float* __restrict__ bk, const float* __restrict__ bv,
    short* __restrict__ qkvb)
{
    __shared__ __align__(16) short abuf[2][128 * 64];
    __shared__ __align__(16) short bbuf[2][128 * 64];
    __shared__ int toks[128];

    const int row0 = blockIdx.x * 128;
    const int n0   = blockIdx.y * 128;
    const int t = threadIdx.x;
    const int lane = t & 63, w = t >> 6;
    const int l15 = lane & 15, lq = lane >> 4;
    const int wr = w >> 1, wc = w & 1;

    if (t < 128) {
        int r = row0 + t;
        toks[t] = xs[r < M1 ? r : M1 - 1];
    }
    __syncthreads();

    f32x4 acc[4][4];
#pragma unroll
    for (int mi = 0; mi < 4; ++mi)
#pragma unroll
        for (int nj = 0; nj < 4; ++nj) { f32x4 z = {0.f,0.f,0.f,0.f}; acc[mi][nj] = z; }

    // staging: linear LDS dest (global_load_lds), pre-swizzled global source (seg ^ row&7)
    auto stage = [&](int buf, int k0) {
#pragma unroll
        for (int i = 0; i < 4; ++i) {
            int idx = (w * 4 + i) * 64 + lane;
            int row = idx >> 3, sp = idx & 7;
            gload16(embb + (size_t)toks[row] * KP + k0 + ((sp ^ (row & 7)) << 3),
                    &abuf[buf][(w * 4 + i) * 512]);
        }
#pragma unroll
        for (int i = 0; i < 4; ++i) {
            int idx = (w * 4 + i) * 64 + lane;
            int row = idx >> 3, sp = idx & 7;
            gload16(wt + (size_t)(n0 + row) * KP + k0 + ((sp ^ (row & 7)) << 3),
                    &bbuf[buf][(w * 4 + i) * 512]);
        }
    };

    stage(0, 0);
    __syncthreads();
    for (int tk = 0; tk < 6; ++tk) {
        if (tk < 5) stage((tk + 1) & 1, (tk + 1) * 64);
        const short* ab = abuf[tk & 1];
        const short* bb = bbuf[tk & 1];
#pragma unroll
        for (int kh = 0; kh < 2; ++kh) {
            short8v af[4], bfv[4];
#pragma unroll
            for (int mi = 0; mi < 4; ++mi) {
                int row = wr * 64 + mi * 16 + l15;
                int sp = (lq + 4 * kh) ^ (row & 7);
                af[mi] = *(const short8v*)(ab + row * 64 + sp * 8);
            }
#pragma unroll
            for (int nj = 0; nj < 4; ++nj) {
                int row = wc * 64 + nj * 16 + l15;
                int sp = (lq + 4 * kh) ^ (row & 7);
                bfv[nj] = *(const short8v*)(bb + row * 64 + sp * 8);
            }
#pragma unroll
            for (int mi = 0; mi < 4; ++mi)
#pragma unroll
                for (int nj = 0; nj < 4; ++nj)
                    acc[mi][nj] = __builtin_amdgcn_mfma_f32_16x16x32_bf16(af[mi], bfv[nj], acc[mi][nj], 0, 0, 0);
        }
        __syncthreads();
    }

    const int mat = n0 >> 9;
    const float* bias = (mat == 0) ? bq : (mat == 1) ? bk : bv;
    const int cb = (n0 & 511) + wc * 64;
#pragma unroll
    for (int nj = 0; nj < 4; ++nj) {
        float bvv = bias[cb + nj * 16 + l15];
        int colg = n0 + wc * 64 + nj * 16 + l15;
#pragma unroll
        for (int mi = 0; mi < 4; ++mi)
#pragma unroll
            for (int r = 0; r < 4; ++r) {
                int rowg = row0 + wr * 64 + mi * 16 + lq * 4 + r;
                if (rowg < M1)
                    qkvb[(size_t)rowg * RS1 + colg] = f2bf(acc[mi][nj][r] + bvv);
            }
    }
}

// ---------------- K2: flash-style MFMA attention with skewed relative scores ----------------
__global__ __launch_bounds__(256) void attn_mfma_kernel(
    const short* __restrict__ qkvb, const short* __restrict__ eb,
    short* __restrict__ attnb)
{
    __shared__ short k_lds[64 * 64];
    __shared__ short v_lds[64 * 64];
    __shared__ short er_lds[144 * 64];
    __shared__ float qe_lds[4][16 * 80];
    __shared__ short p_lds[4][16 * 64];

    const int bid = blockIdx.x;
    const int bh = bid / 6, qt = bid - bh * 6;
    const int b = bh >> 3, h = bh & 7;
    const int i0 = qt * 64;
    const int t = threadIdx.x;
    const int lane = t & 63, w = t >> 6;
    const int l15 = lane & 15, lq = lane >> 4;
    const size_t qbase = (size_t)b * SS * RS1 + h * 64;

    const int iw = i0 + 16 * w;
    int qr = iw + l15; if (qr > SS - 1) qr = SS - 1;
    const short8v qa0 = *(const short8v*)(qkvb + qbase + (size_t)qr * RS1 + lq * 8);
    const short8v qa1 = *(const short8v*)(qkvb + qbase + (size_t)qr * RS1 + 32 + lq * 8);

    float m[4], l[4];
    f32x4 o[4];
#pragma unroll
    for (int r = 0; r < 4; ++r) { m[r] = -1e30f; l[r] = 0.f; }
#pragma unroll
    for (int nd = 0; nd < 4; ++nd) { f32x4 z = {0.f, 0.f, 0.f, 0.f}; o[nd] = z; }

    const int nst = qt + 1;
    for (int js = 0; js < nst; ++js) {
        const int j0 = js * 64;
        __syncthreads();
#pragma unroll
        for (int it = 0; it < 2; ++it) {
            int task = t + 256 * it;
            int row = task >> 3, c = task & 7;
            int jg = j0 + row; if (jg > SS - 1) jg = SS - 1;
            short8v kv = *(const short8v*)(qkvb + qbase + 512 + (size_t)jg * RS1 + c * 8);
            *(short8v*)((char*)k_lds + ((row * 128 + c * 16) ^ ((row & 7) << 4))) = kv;
        }
        if (t < 128) {
            int qd = t >> 3, c = t & 7;
            int j00 = j0 + qd * 4;
            int ja  = j00     > SS - 1 ? SS - 1 : j00;
            int jb2 = j00 + 1 > SS - 1 ? SS - 1 : j00 + 1;
            int jc  = j00 + 2 > SS - 1 ? SS - 1 : j00 + 2;
            int jd2 = j00 + 3 > SS - 1 ? SS - 1 : j00 + 3;
            const short* vpb = qkvb + qbase + 1024;
            short8v r0 = *(const short8v*)(vpb + (size_t)ja  * RS1 + c * 8);
            short8v r1 = *(const short8v*)(vpb + (size_t)jb2 * RS1 + c * 8);
            short8v r2 = *(const short8v*)(vpb + (size_t)jc  * RS1 + c * 8);
            short8v r3 = *(const short8v*)(vpb + (size_t)jd2 * RS1 + c * 8);
#pragma unroll
            for (int dd = 0; dd < 8; ++dd) {
                int d = c * 8 + dd;
                short4v pk; pk[0] = r0[dd]; pk[1] = r1[dd]; pk[2] = r2[dd]; pk[3] = r3[dd];
                *(short4v*)((char*)v_lds + ((d * 128 + qd * 8) ^ ((d & 7) << 4))) = pk;
            }
        }
        const int l0blk = SS - 64 - i0 + j0;
#pragma unroll
        for (int it = 0; it < 5; ++it) {
            int task = t + 256 * it;
            if (task < 144 * 8) {
                int row = task >> 3, c = task & 7;
                int lg = l0blk + row;
                lg = lg < 0 ? 0 : (lg > SS - 1 ? SS - 1 : lg);
                short8v ev = *(const short8v*)(eb + (size_t)lg * DH + c * 8);
                *(short8v*)((char*)er_lds + ((row * 128 + c * 16) ^ ((row & 7) << 4))) = ev;
            }
        }
        __syncthreads();

        const int sbase = 48 - 16 * w;
        f32x4 qe[5];
#pragma unroll
        for (int n2 = 0; n2 < 5; ++n2) {
            int slot = sbase + n2 * 16 + l15;
            short8v e0 = *(const short8v*)((char*)er_lds + ((slot * 128 + lq * 16) ^ ((slot & 7) << 4)));
            short8v e1 = *(const short8v*)((char*)er_lds + ((slot * 128 + 64 + lq * 16) ^ ((slot & 7) << 4)));
            f32x4 z = {0.f, 0.f, 0.f, 0.f};
            z = __builtin_amdgcn_mfma_f32_16x16x32_bf16(qa0, e0, z, 0, 0, 0);
            qe[n2] = __builtin_amdgcn_mfma_f32_16x16x32_bf16(qa1, e1, z, 0, 0, 0);
        }
        float* qeb = qe_lds[w];
#pragma unroll
        for (int n2 = 0; n2 < 5; ++n2)
#pragma unroll
            for (int r = 0; r < 4; ++r)
                qeb[(lq * 4 + r) * 80 + n2 * 16 + l15] = qe[n2][r];

        f32x4 sc[4];
#pragma unroll
        for (int n = 0; n < 4; ++n) {
            int row = n * 16 + l15;
            short8v k0 = *(const short8v*)((char*)k_lds + ((row * 128 + lq * 16) ^ ((row & 7) << 4)));
            short8v k1 = *(const short8v*)((char*)k_lds + ((row * 128 + 64 + lq * 16) ^ ((row & 7) << 4)));
            f32x4 z = {0.f, 0.f, 0.f, 0.f};
            z = __builtin_amdgcn_mfma_f32_16x16x32_bf16(qa0, k0, z, 0, 0, 0);
            sc[n] = __builtin_amdgcn_mfma_f32_16x16x32_bf16(qa1, k1, z, 0, 0, 0);
        }

#pragma unroll
        for (int n = 0; n < 4; ++n)
#pragma unroll
            for (int r = 0; r < 4; ++r) {
                int irel = lq * 4 + r;
                int jrel = n * 16 + l15;
                float srel = qeb[irel * 80 + (15 - irel + jrel)];
                float s = (sc[n][r] + srel) * 0.125f;
                bool ok = (j0 + jrel) <= (iw + irel);
                sc[n][r] = ok ? s : -1e9f;
            }

        float scale[4];
#pragma unroll
        for (int r = 0; r < 4; ++r) {
            float mx = fmaxf(fmaxf(sc[0][r], sc[1][r]), fmaxf(sc[2][r], sc[3][r]));
            mx = fmaxf(mx, __shfl_xor(mx, 1));
            mx = fmaxf(mx, __shfl_xor(mx, 2));
            mx = fmaxf(mx, __shfl_xor(mx, 4));
            mx = fmaxf(mx, __shfl_xor(mx, 8));
            float mn = fmaxf(m[r], mx);
            scale[r] = __expf(m[r] - mn);
            m[r] = mn;
            float ps = 0.f;
#pragma unroll
            for (int n = 0; n < 4; ++n) {
                float p = __expf(sc[n][r] - mn);
                sc[n][r] = p;
                ps += p;
            }
            ps += __shfl_xor(ps, 1);
            ps += __shfl_xor(ps, 2);
            ps += __shfl_xor(ps, 4);
            ps += __shfl_xor(ps, 8);
            l[r] = l[r] * scale[r] + ps;
        }

        short* pw = p_lds[w];
#pragma unroll
        for (int n = 0; n < 4; ++n)
#pragma unroll
            for (int r = 0; r < 4; ++r) {
                int irel = lq * 4 + r;
                int jrel = n * 16 + l15;
                *(short*)((char*)pw + ((irel * 128 + jrel * 2) ^ ((irel & 7) << 4))) = f2bf(sc[n][r]);
            }

#pragma unroll
        for (int nd = 0; nd < 4; ++nd)
#pragma unroll
            for (int r = 0; r < 4; ++r)
                o[nd][r] *= scale[r];

#pragma unroll
        for (int kb2 = 0; kb2 < 2; ++kb2) {
            short8v pa = *(const short8v*)((char*)pw + ((l15 * 128 + kb2 * 64 + lq * 16) ^ ((l15 & 7) << 4)));
#pragma unroll
            for (int nd = 0; nd < 4; ++nd) {
                int d = nd * 16 + l15;
                short8v vf = *(const short8v*)((char*)v_lds + ((d * 128 + kb2 * 64 + lq * 16) ^ ((d & 7) << 4)));
                o[nd] = __builtin_amdgcn_mfma_f32_16x16x32_bf16(pa, vf, o[nd], 0, 0, 0);
            }
        }
    }

#pragma unroll
    for (int r = 0; r < 4; ++r) {
        int i = iw + lq * 4 + r;
        if (i < SS) {
            float rl = 1.0f / l[r];
#pragma unroll
            for (int nd = 0; nd < 4; ++nd)
                attnb[(size_t)(b * SS + i) * NI + h * 64 + nd * 16 + l15] = f2bf(o[nd][r] * rl);
        }
    }
}

// ---------------- K3: out = attnb[M1,512] @ wot^T + bo, f32 out ----------------
__global__ __launch_bounds__(256) void oproj_mfma_kernel(
    const short* __restrict__ ab_g, const short* __restrict__ wot,
    const float* __restrict__ bo, float* __restrict__ out)
{
    __shared__ __align__(16) short abuf[2][128 * 64];
    __shared__ __align__(16) short bbuf[2][128 * 64];

    const int row0 = blockIdx.x * 128;
    const int n0   = blockIdx.y * 128;
    const int t = threadIdx.x;
    const int lane = t & 63, w = t >> 6;
    const int l15 = lane & 15, lq = lane >> 4;
    const int wr = w >> 1, wc = w & 1;

    f32x4 acc[4][4];
#pragma unroll
    for (int mi = 0; mi < 4; ++mi)
#pragma unroll
        for (int nj = 0; nj < 4; ++nj) { f32x4 z = {0.f,0.f,0.f,0.f}; acc[mi][nj] = z; }

    auto stage = [&](int buf, int k0) {
#pragma unroll
        for (int i = 0; i < 4; ++i) {
            int idx = (w * 4 + i) * 64 + lane;
            int row = idx >> 3, sp = idx & 7;
            int rg = row0 + row; rg = rg < M1 ? rg : M1 - 1;
            gload16(ab_g + (size_t)rg * NI + k0 + ((sp ^ (row & 7)) << 3),
                    &abuf[buf][(w * 4 + i) * 512]);
        }
#pragma unroll
        for (int i = 0; i < 4; ++i) {
            int idx = (w * 4 + i) * 64 + lane;
            int row = idx >> 3, sp = idx & 7;
            gload16(wot + (size_t)(n0 + row) * NI + k0 + ((sp ^ (row & 7)) << 3),
                    &bbuf[buf][(w * 4 + i) * 512]);
        }
    };

    stage(0, 0);
    __syncthreads();
    for (int tk = 0; tk < 8; ++tk) {
        if (tk < 7) stage((tk + 1) & 1, (tk + 1) * 64);
        const short* ab = abuf[tk & 1];
        const short* bb = bbuf[tk & 1];
#pragma unroll
        for (int kh = 0; kh < 2; ++kh) {
            short8v af[4], bfv[4];
#pragma unroll
            for (int mi = 0; mi < 4; ++mi) {
                int row = wr * 64 + mi * 16 + l15;
                int sp = (lq + 4 * kh) ^ (row & 7);
                af[mi] = *(const short8v*)(ab + row * 64 + sp * 8);
            }
#pragma unroll
            for (int nj = 0; nj < 4; ++nj) {
                int row = wc * 64 + nj * 16 + l15;
                int sp = (lq + 4 * kh) ^ (row & 7);
                bfv[nj] = *(const short8v*)(bb + row * 64 + sp * 8);
            }
#pragma unroll
            for (int mi = 0; mi < 4; ++mi)
#pragma unroll
                for (int nj = 0; nj < 4; ++nj)
                    acc[mi][nj] = __builtin_amdgcn_mfma_f32_16x16x32_bf16(af[mi], bfv[nj], acc[mi][nj], 0, 0, 0);
        }
        __syncthreads();
    }

#pragma unroll
    for (int nj = 0; nj < 4; ++nj) {
        int colg = n0 + wc * 64 + nj * 16 + l15;
        float bvv = (colg < DM) ? bo[colg] : 0.f;
#pragma unroll
        for (int mi = 0; mi < 4; ++mi)
#pragma unroll
            for (int r = 0; r < 4; ++r) {
                int rowg = row0 + wr * 64 + mi * 16 + lq * 4 + r;
                if (rowg < M1 && colg < DM)
                    out[(size_t)rowg * DM + colg] = acc[mi][nj][r] + bvv;
            }
    }
}

extern "C" void kernel_launch(void* const* d_in, const int* in_sizes, int n_in,
                              void* d_out, int out_size, void* d_ws, size_t ws_size,
                              hipStream_t stream) {
    const int*   xs  = (const int*)d_in[0];
    const float* emb = (const float*)d_in[1];
    const float* Wq  = (const float*)d_in[2];
    const float* bq  = (const float*)d_in[3];
    const float* Wk  = (const float*)d_in[4];
    const float* bk  = (const float*)d_in[5];
    const float* Wv  = (const float*)d_in[6];
    const float* bv  = (const float*)d_in[7];
    const float* Er  = (const float*)d_in[8];
    const float* Wo  = (const float*)d_in[9];
    const float* bo  = (const float*)d_in[10];
    float* out = (float*)d_out;

    short* qkvb = (short*)d_ws;                        // M1*1536
    short* attnb = qkvb + (size_t)M1 * NQ;             // M1*512
    short* embb = attnb + (size_t)M1 * NI;             // DM*KP
    short* wt   = embb + (size_t)DM * KP;              // NQ*KP
    short* wot  = wt + (size_t)NQ * KP;                // 384*NI
    short* eb   = wot + (size_t)384 * NI;              // SS*DH

    er_conv_kernel<<<(SS * DH + 255) / 256, 256, 0, stream>>>(Er, eb);
    emb_conv_kernel<<<(DM * KP + 255) / 256, 256, 0, stream>>>(emb, embb);
    w_conv_kernel<<<(NQ * KP + 255) / 256, 256, 0, stream>>>(Wq, Wk, Wv, wt);
    wo_conv_kernel<<<(384 * NI + 255) / 256, 256, 0, stream>>>(Wo, wot);

    dim3 g1((M1 + 127) / 128, 12);
    qkv_mfma_kernel<<<g1, 256, 0, stream>>>(xs, embb, wt, bq, bk, bv, qkvb);
    attn_mfma_kernel<<<BB * NH * 6, 256, 0, stream>>>(qkvb, eb, attnb);
    dim3 g3((M1 + 127) / 128, 3);
    oproj_mfma_kernel<<<g3, 256, 0, stream>>>(attnb, wot, bo, out);
}